// Round 1
// baseline (119.927 us; speedup 1.0000x reference)
//
#include <hip/hip_runtime.h>

// Problem constants: B=16, C=3, H=W=512.
// priority(b,y,x) = min(eye+mouth, 1), eye = clip(1 - sqrt(min d2 over pts36..47)/15, 0, 1),
// mouth same over pts 48..67.  weight = 1 + 299*priority.  out = mean(|pred-target|*weight).
//
// R1 change vs baseline: 2 float4-groups per thread (12 global loads in flight,
// issued before the ~640-op distance compute), halving wave count 16384->8192 and
// per-wave fixed overhead (LDS staging, barrier, shuffle tree, partial write).
// Arithmetic per pixel is bit-identical to the previous passing kernel.

constexpr int   kW        = 512;
constexpr int   kG        = 512 * 512 / 4;   // float4 groups per plane = 65536
constexpr int   kThreads  = 256;
constexpr int   kGPT      = 2;               // groups per thread
constexpr int   kSpan     = kThreads * kGPT; // 512 groups per block
constexpr int   kBlocksX  = kG / kSpan;      // 128 blocks per batch
constexpr int   kBlocks   = kBlocksX * 16;   // 2048 total
constexpr float kInvR     = 1.0f / 15.0f;
constexpr float kInvN     = 1.0f / (16.0f * 3.0f * 512.0f * 512.0f);

__device__ __forceinline__ float clamp01(float v) {
    return fminf(fmaxf(v, 0.0f), 1.0f);
}

// Compute the 4 per-pixel weights for float4-group g (same math as baseline).
__device__ __forceinline__ void weights4(int g,
                                         const float* __restrict__ s_cx,
                                         const float* __restrict__ s_cy,
                                         float& w0, float& w1, float& w2, float& w3) {
    const float y  = (float)(g >> 7);
    const float x0 = (float)((g & 127) << 2);
    const float x1 = x0 + 1.0f, x2 = x0 + 2.0f, x3 = x0 + 3.0f;

    float de0 = 1e30f, de1 = 1e30f, de2 = 1e30f, de3 = 1e30f;  // eye min d^2
    float dm0 = 1e30f, dm1 = 1e30f, dm2 = 1e30f, dm3 = 1e30f;  // mouth min d^2

#pragma unroll
    for (int j = 0; j < 12; ++j) {               // eye points
        const float dy  = y - s_cy[j];
        const float dy2 = dy * dy;
        float dx;
        dx = x0 - s_cx[j]; de0 = fminf(de0, fmaf(dx, dx, dy2));
        dx = x1 - s_cx[j]; de1 = fminf(de1, fmaf(dx, dx, dy2));
        dx = x2 - s_cx[j]; de2 = fminf(de2, fmaf(dx, dx, dy2));
        dx = x3 - s_cx[j]; de3 = fminf(de3, fmaf(dx, dx, dy2));
    }
#pragma unroll
    for (int j = 12; j < 32; ++j) {              // mouth points
        const float dy  = y - s_cy[j];
        const float dy2 = dy * dy;
        float dx;
        dx = x0 - s_cx[j]; dm0 = fminf(dm0, fmaf(dx, dx, dy2));
        dx = x1 - s_cx[j]; dm1 = fminf(dm1, fmaf(dx, dx, dy2));
        dx = x2 - s_cx[j]; dm2 = fminf(dm2, fmaf(dx, dx, dy2));
        dx = x3 - s_cx[j]; dm3 = fminf(dm3, fmaf(dx, dx, dy2));
    }

    const float e0 = clamp01(1.0f - sqrtf(de0) * kInvR);
    const float e1 = clamp01(1.0f - sqrtf(de1) * kInvR);
    const float e2 = clamp01(1.0f - sqrtf(de2) * kInvR);
    const float e3 = clamp01(1.0f - sqrtf(de3) * kInvR);
    const float m0 = clamp01(1.0f - sqrtf(dm0) * kInvR);
    const float m1 = clamp01(1.0f - sqrtf(dm1) * kInvR);
    const float m2 = clamp01(1.0f - sqrtf(dm2) * kInvR);
    const float m3 = clamp01(1.0f - sqrtf(dm3) * kInvR);

    w0 = fmaf(299.0f, fminf(e0 + m0, 1.0f), 1.0f);
    w1 = fmaf(299.0f, fminf(e1 + m1, 1.0f), 1.0f);
    w2 = fmaf(299.0f, fminf(e2 + m2, 1.0f), 1.0f);
    w3 = fmaf(299.0f, fminf(e3 + m3, 1.0f), 1.0f);
}

// Weighted |p-t| accumulate for one group's 3 channel-pairs (2 chains, merged).
__device__ __forceinline__ float consume(const float4& p0, const float4& p1, const float4& p2,
                                         const float4& t0, const float4& t1, const float4& t2,
                                         float w0, float w1, float w2, float w3) {
    float accA = 0.0f, accB = 0.0f;
    accA = fmaf(fabsf(p0.x - t0.x), w0, accA);
    accB = fmaf(fabsf(p0.y - t0.y), w1, accB);
    accA = fmaf(fabsf(p0.z - t0.z), w2, accA);
    accB = fmaf(fabsf(p0.w - t0.w), w3, accB);
    accA = fmaf(fabsf(p1.x - t1.x), w0, accA);
    accB = fmaf(fabsf(p1.y - t1.y), w1, accB);
    accA = fmaf(fabsf(p1.z - t1.z), w2, accA);
    accB = fmaf(fabsf(p1.w - t1.w), w3, accB);
    accA = fmaf(fabsf(p2.x - t2.x), w0, accA);
    accB = fmaf(fabsf(p2.y - t2.y), w1, accB);
    accA = fmaf(fabsf(p2.z - t2.z), w2, accA);
    accB = fmaf(fabsf(p2.w - t2.w), w3, accB);
    return accA + accB;
}

__global__ __launch_bounds__(kThreads) void eml_main(
        const float* __restrict__ pred,
        const float* __restrict__ target,
        const int*   __restrict__ lm,      // (16, 68, 2) int32
        float*       __restrict__ partial) // kBlocks floats
{
    __shared__ float s_cx[32], s_cy[32];
    const int b   = blockIdx.y;
    const int tid = threadIdx.x;

    if (tid < 32) {
        const int j  = 36 + tid;                 // points 36..67
        int xi = lm[b * 136 + j * 2 + 0];
        int yi = lm[b * 136 + j * 2 + 1];
        xi = min(max(xi, 0), kW - 1);
        yi = min(max(yi, 0), kW - 1);
        s_cx[tid] = (float)xi;
        s_cy[tid] = (float)yi;
    }
    __syncthreads();

    const int g0 = blockIdx.x * kSpan + tid;     // first group in batch plane
    const int g1 = g0 + kThreads;                // second group (coalesced pair)

    const float4* __restrict__ pred4 = (const float4*)pred   + (size_t)b * 3 * kG;
    const float4* __restrict__ tgt4  = (const float4*)target + (size_t)b * 3 * kG;

    // ---- issue ALL 12 global loads first; latency hides behind distance compute
    const float4 pa0 = pred4[0 * kG + g0];
    const float4 pa1 = pred4[1 * kG + g0];
    const float4 pa2 = pred4[2 * kG + g0];
    const float4 ta0 = tgt4[0 * kG + g0];
    const float4 ta1 = tgt4[1 * kG + g0];
    const float4 ta2 = tgt4[2 * kG + g0];
    const float4 pb0 = pred4[0 * kG + g1];
    const float4 pb1 = pred4[1 * kG + g1];
    const float4 pb2 = pred4[2 * kG + g1];
    const float4 tb0 = tgt4[0 * kG + g1];
    const float4 tb1 = tgt4[1 * kG + g1];
    const float4 tb2 = tgt4[2 * kG + g1];

    // ---- group 0: ~320 VALU ops of weight compute, then consume its loads
    float w0, w1, w2, w3;
    weights4(g0, s_cx, s_cy, w0, w1, w2, w3);
    float acc = consume(pa0, pa1, pa2, ta0, ta1, ta2, w0, w1, w2, w3);

    // ---- group 1: its loads had the entire group-0 compute to land
    weights4(g1, s_cx, s_cy, w0, w1, w2, w3);
    acc += consume(pb0, pb1, pb2, tb0, tb1, tb2, w0, w1, w2, w3);

    // wave (64-lane) shuffle reduction
#pragma unroll
    for (int off = 32; off > 0; off >>= 1)
        acc += __shfl_down(acc, off, 64);

    __shared__ float s_wsum[4];
    const int lane = tid & 63;
    const int wid  = tid >> 6;
    if (lane == 0) s_wsum[wid] = acc;
    __syncthreads();
    if (tid == 0)
        partial[b * kBlocksX + blockIdx.x] = s_wsum[0] + s_wsum[1] + s_wsum[2] + s_wsum[3];
}

__global__ __launch_bounds__(256) void eml_finish(
        const float* __restrict__ partial,   // kBlocks = 2048 floats
        float*       __restrict__ out)
{
    const int tid = threadIdx.x;
    float v = 0.0f;
#pragma unroll
    for (int k = 0; k < kBlocks / 256; ++k)      // 8 strided reads
        v += partial[tid + k * 256];
#pragma unroll
    for (int off = 32; off > 0; off >>= 1)
        v += __shfl_down(v, off, 64);

    __shared__ float s_wsum[4];
    if ((tid & 63) == 0) s_wsum[tid >> 6] = v;
    __syncthreads();
    if (tid == 0)
        out[0] = (s_wsum[0] + s_wsum[1] + s_wsum[2] + s_wsum[3]) * kInvN;
}

extern "C" void kernel_launch(void* const* d_in, const int* in_sizes, int n_in,
                              void* d_out, int out_size, void* d_ws, size_t ws_size,
                              hipStream_t stream) {
    const float* pred   = (const float*)d_in[0];
    const float* target = (const float*)d_in[1];
    const int*   lm     = (const int*)d_in[2];
    float* out     = (float*)d_out;
    float* partial = (float*)d_ws;               // 8 KiB used

    dim3 grid(kBlocksX, 16);
    eml_main<<<grid, kThreads, 0, stream>>>(pred, target, lm, partial);
    eml_finish<<<1, 256, 0, stream>>>(partial, out);
}

// Round 3
// 115.516 us; speedup vs baseline: 1.0382x; 1.0382x over previous
//
#include <hip/hip_runtime.h>

// Problem constants: B=16, C=3, H=W=512.
// priority(b,y,x) = min(eye+mouth, 1), eye = clip(1 - sqrt(min d2 over pts36..47)/15, 0, 1),
// mouth same over pts 48..67.  weight = 1 + 299*priority.  out = mean(|pred-target|*weight).
//
// R3 = R2 resubmit (R2 bench was an infra failure, not a kernel verdict).
// R2 change: per-block landmark CULLING. Each block covers exactly 2 rows; only
// landmarks with cy in [y0-15, y0+16] can contribute nonzero region value
// (RADIUS=15), expected ~2 of 32 points. Lanes 0..31 ballot-compact qualifying
// points into LDS (eye list then mouth list); all threads loop only over those.
// Exactly value-preserving: excluded points have d^2 > 225 for every strip
// pixel, so clamp01(1 - sqrt(d2)/15) == 0.0f identically.
// VALU ~450 -> ~60 ops/thread; memory traffic unchanged (1 float4-group/thread,
// reverted from R1's 2-group variant which was neutral-to-negative).

constexpr int   kW        = 512;
constexpr int   kG        = 512 * 512 / 4;   // float4 groups per plane = 65536
constexpr int   kThreads  = 256;
constexpr int   kBlocksX  = kG / kThreads;   // 256 blocks per batch (2 rows each)
constexpr int   kBlocks   = kBlocksX * 16;   // 4096 total
constexpr float kInvR     = 1.0f / 15.0f;
constexpr float kInvN     = 1.0f / (16.0f * 3.0f * 512.0f * 512.0f);

__device__ __forceinline__ float clamp01(float v) {
    return fminf(fmaxf(v, 0.0f), 1.0f);
}

__global__ __launch_bounds__(kThreads) void eml_main(
        const float* __restrict__ pred,
        const float* __restrict__ target,
        const int*   __restrict__ lm,      // (16, 68, 2) int32
        float*       __restrict__ partial) // kBlocks floats
{
    __shared__ float s_px[32], s_py[32];   // compacted qualifying points (eye, then mouth)
    __shared__ int   s_ke, s_km;

    const int b   = blockIdx.y;
    const int tid = threadIdx.x;
    const int g   = blockIdx.x * kThreads + tid;   // float4-group within batch plane

    const float4* __restrict__ pred4 = (const float4*)pred   + (size_t)b * 3 * kG;
    const float4* __restrict__ tgt4  = (const float4*)target + (size_t)b * 3 * kG;

    // ---- issue ALL 6 big global loads first; latency hides behind everything below
    const float4 p0 = pred4[0 * kG + g];
    const float4 p1 = pred4[1 * kG + g];
    const float4 p2 = pred4[2 * kG + g];
    const float4 t0 = tgt4[0 * kG + g];
    const float4 t1 = tgt4[1 * kG + g];
    const float4 t2 = tgt4[2 * kG + g];

    // ---- lanes 0..31 of wave 0: load landmarks, cull to this block's 2-row strip,
    //      ballot-compact survivors into LDS.
    if (tid < 32) {
        const int j  = 36 + tid;                 // points 36..67
        int xi = lm[b * 136 + j * 2 + 0];
        int yi = lm[b * 136 + j * 2 + 1];
        xi = min(max(xi, 0), kW - 1);
        yi = min(max(yi, 0), kW - 1);

        const int  y0   = blockIdx.x * 2;        // first row of this block's strip
        const bool keep = (yi >= y0 - 15) && (yi <= y0 + 16);

        const unsigned long long m    = __ballot(keep);
        const unsigned long long eyeM = m & 0x0000000000000FFFULL;   // lanes 0..11
        const unsigned long long mouM = m & 0x00000000FFFFF000ULL;   // lanes 12..31
        const int ke = __popcll(eyeM);

        if (keep) {
            const unsigned long long below = m & ((1ULL << tid) - 1ULL);
            const int pos = (tid < 12) ? __popcll(below & eyeM)
                                       : ke + __popcll(below & mouM);
            s_px[pos] = (float)xi;
            s_py[pos] = (float)yi;
        }
        if (tid == 0) {
            s_ke = ke;
            s_km = __popcll(mouM);
        }
    }
    __syncthreads();

    const int ke = s_ke;
    const int km = s_km;

    // ---- distance / weight compute over ONLY the qualifying points
    const float y  = (float)(g >> 7);
    const float x0 = (float)((g & 127) << 2);
    const float x1 = x0 + 1.0f, x2 = x0 + 2.0f, x3 = x0 + 3.0f;

    float de0 = 1e30f, de1 = 1e30f, de2 = 1e30f, de3 = 1e30f;  // eye min d^2
    float dm0 = 1e30f, dm1 = 1e30f, dm2 = 1e30f, dm3 = 1e30f;  // mouth min d^2

    for (int i = 0; i < ke; ++i) {               // qualifying eye points (usually 0-1)
        const float cy  = s_py[i];
        const float cx  = s_px[i];
        const float dy  = y - cy;
        const float dy2 = dy * dy;
        float dx;
        dx = x0 - cx; de0 = fminf(de0, fmaf(dx, dx, dy2));
        dx = x1 - cx; de1 = fminf(de1, fmaf(dx, dx, dy2));
        dx = x2 - cx; de2 = fminf(de2, fmaf(dx, dx, dy2));
        dx = x3 - cx; de3 = fminf(de3, fmaf(dx, dx, dy2));
    }
    const int n = ke + km;
    for (int i = ke; i < n; ++i) {               // qualifying mouth points (usually 0-2)
        const float cy  = s_py[i];
        const float cx  = s_px[i];
        const float dy  = y - cy;
        const float dy2 = dy * dy;
        float dx;
        dx = x0 - cx; dm0 = fminf(dm0, fmaf(dx, dx, dy2));
        dx = x1 - cx; dm1 = fminf(dm1, fmaf(dx, dx, dy2));
        dx = x2 - cx; dm2 = fminf(dm2, fmaf(dx, dx, dy2));
        dx = x3 - cx; dm3 = fminf(dm3, fmaf(dx, dx, dy2));
    }

    const float e0 = clamp01(1.0f - sqrtf(de0) * kInvR);
    const float e1 = clamp01(1.0f - sqrtf(de1) * kInvR);
    const float e2 = clamp01(1.0f - sqrtf(de2) * kInvR);
    const float e3 = clamp01(1.0f - sqrtf(de3) * kInvR);
    const float m0 = clamp01(1.0f - sqrtf(dm0) * kInvR);
    const float m1 = clamp01(1.0f - sqrtf(dm1) * kInvR);
    const float m2 = clamp01(1.0f - sqrtf(dm2) * kInvR);
    const float m3 = clamp01(1.0f - sqrtf(dm3) * kInvR);

    const float w0 = fmaf(299.0f, fminf(e0 + m0, 1.0f), 1.0f);
    const float w1 = fmaf(299.0f, fminf(e1 + m1, 1.0f), 1.0f);
    const float w2 = fmaf(299.0f, fminf(e2 + m2, 1.0f), 1.0f);
    const float w3 = fmaf(299.0f, fminf(e3 + m3, 1.0f), 1.0f);

    // ---- consume loads (2 independent accumulator chains, merged at end)
    float accA = 0.0f, accB = 0.0f;
    accA = fmaf(fabsf(p0.x - t0.x), w0, accA);
    accB = fmaf(fabsf(p0.y - t0.y), w1, accB);
    accA = fmaf(fabsf(p0.z - t0.z), w2, accA);
    accB = fmaf(fabsf(p0.w - t0.w), w3, accB);
    accA = fmaf(fabsf(p1.x - t1.x), w0, accA);
    accB = fmaf(fabsf(p1.y - t1.y), w1, accB);
    accA = fmaf(fabsf(p1.z - t1.z), w2, accA);
    accB = fmaf(fabsf(p1.w - t1.w), w3, accB);
    accA = fmaf(fabsf(p2.x - t2.x), w0, accA);
    accB = fmaf(fabsf(p2.y - t2.y), w1, accB);
    accA = fmaf(fabsf(p2.z - t2.z), w2, accA);
    accB = fmaf(fabsf(p2.w - t2.w), w3, accB);
    float acc = accA + accB;

    // wave (64-lane) shuffle reduction
#pragma unroll
    for (int off = 32; off > 0; off >>= 1)
        acc += __shfl_down(acc, off, 64);

    __shared__ float s_wsum[4];
    const int lane = tid & 63;
    const int wid  = tid >> 6;
    if (lane == 0) s_wsum[wid] = acc;
    __syncthreads();
    if (tid == 0)
        partial[b * kBlocksX + blockIdx.x] = s_wsum[0] + s_wsum[1] + s_wsum[2] + s_wsum[3];
}

__global__ __launch_bounds__(256) void eml_finish(
        const float* __restrict__ partial,   // kBlocks = 4096 floats
        float*       __restrict__ out)
{
    const int tid = threadIdx.x;
    float v = 0.0f;
#pragma unroll
    for (int k = 0; k < kBlocks / 256; ++k)      // 16 strided reads
        v += partial[tid + k * 256];
#pragma unroll
    for (int off = 32; off > 0; off >>= 1)
        v += __shfl_down(v, off, 64);

    __shared__ float s_wsum[4];
    if ((tid & 63) == 0) s_wsum[tid >> 6] = v;
    __syncthreads();
    if (tid == 0)
        out[0] = (s_wsum[0] + s_wsum[1] + s_wsum[2] + s_wsum[3]) * kInvN;
}

extern "C" void kernel_launch(void* const* d_in, const int* in_sizes, int n_in,
                              void* d_out, int out_size, void* d_ws, size_t ws_size,
                              hipStream_t stream) {
    const float* pred   = (const float*)d_in[0];
    const float* target = (const float*)d_in[1];
    const int*   lm     = (const int*)d_in[2];
    float* out     = (float*)d_out;
    float* partial = (float*)d_ws;               // 16 KiB used

    dim3 grid(kBlocksX, 16);
    eml_main<<<grid, kThreads, 0, stream>>>(pred, target, lm, partial);
    eml_finish<<<1, 256, 0, stream>>>(partial, out);
}